// Round 3
// baseline (237.218 us; speedup 1.0000x reference)
//
#include <hip/hip_runtime.h>
#include <math.h>

// CRDLoss on MI355X.
// Phase 1: embed (GEMM 8192x2048x128 + bias + L2 norm) -> fp16 embeddings in ws.
// Phase 2: 8192x8192 similarity via f16 MFMA, fused exp/log epilogue, per-block
//          double partial sums (deterministic, no atomics).
// Phase 3: reduce 4096 partials -> out[0] = -(sum)/B.
//
// R2 note: two consecutive container failures on this source; only unverifiable
// assumption was ws_size >= 4.25 MB. kernel_launch now guards on ws_size so an
// undersized workspace produces a readable bench failure, not a memory fault.

typedef _Float16 half_t;
typedef half_t halfx4 __attribute__((ext_vector_type(4)));
typedef half_t halfx8 __attribute__((ext_vector_type(8)));
typedef float f32x4 __attribute__((ext_vector_type(4)));

#define B_TOT   8192
#define K_EMB   2048
#define F_DIM   128
#define INV_T   14.285714285714286f   // 1/0.07
#define EPS_C   0.97f
#define LOG_EPS (-0.030459207485f)    // ln(0.97)

// ---------------------------------------------------------------------------
// Embed: 64-row tile x all 128 cols, BK=64.  grid = (128, 2); block = 256.
// ---------------------------------------------------------------------------
__global__ __launch_bounds__(256) void embed_kernel(
    const float* __restrict__ Xs, const float* __restrict__ Xt,
    const float* __restrict__ Ws, const float* __restrict__ Wt,
    const float* __restrict__ bs, const float* __restrict__ bt,
    half_t* __restrict__ outs, half_t* __restrict__ outt)
{
    const float* X; const float* W; const float* bias; half_t* out;
    if (blockIdx.y == 0) { X = Xs; W = Ws; bias = bs; out = outs; }
    else                 { X = Xt; W = Wt; bias = bt; out = outt; }

    // +8 pad: row stride 72 halves = 144 B (16B-aligned -> 2-way max conflict)
    __shared__ half_t As[64][72];
    __shared__ half_t Bs[128][72];
    __shared__ float  biasS[128];
    __shared__ float  redS[64][2];
    __shared__ float  invS[64];

    const int tid = threadIdx.x;
    const int r0  = blockIdx.x * 64;
    if (tid < 128) biasS[tid] = bias[tid];

    const int lane = tid & 63;
    const int w    = tid >> 6;
    const int wm   = w >> 1, wn = w & 1;   // wave quadrant: rows 32*wm, cols 64*wn
    const int l16  = lane & 15, lhi = lane >> 4;

    f32x4 acc[2][4];
    for (int im = 0; im < 2; ++im)
        for (int in = 0; in < 4; ++in)
            acc[im][in] = f32x4{0.f, 0.f, 0.f, 0.f};

    for (int kb = 0; kb < K_EMB; kb += 64) {
        // stage A: 64 rows x 64 k = 1024 float4, 4 per thread
        for (int i = 0; i < 4; ++i) {
            int f = tid + i * 256;
            int row = f >> 4, kq = f & 15;
            float4 v = *(const float4*)(X + (size_t)(r0 + row) * K_EMB + kb + kq * 4);
            halfx4 h4 = {(half_t)v.x, (half_t)v.y, (half_t)v.z, (half_t)v.w};
            *(halfx4*)&As[row][kq * 4] = h4;
        }
        // stage B (W): 128 rows x 64 k = 2048 float4, 8 per thread
        for (int i = 0; i < 8; ++i) {
            int f = tid + i * 256;
            int row = f >> 4, kq = f & 15;
            float4 v = *(const float4*)(W + (size_t)row * K_EMB + kb + kq * 4);
            halfx4 h4 = {(half_t)v.x, (half_t)v.y, (half_t)v.z, (half_t)v.w};
            *(halfx4*)&Bs[row][kq * 4] = h4;
        }
        __syncthreads();
        for (int kk = 0; kk < 2; ++kk) {
            halfx8 a[2], b[4];
            for (int im = 0; im < 2; ++im)
                a[im] = *(const halfx8*)&As[wm * 32 + im * 16 + l16][kk * 32 + lhi * 8];
            for (int in = 0; in < 4; ++in)
                b[in] = *(const halfx8*)&Bs[wn * 64 + in * 16 + l16][kk * 32 + lhi * 8];
            for (int im = 0; im < 2; ++im)
                for (int in = 0; in < 4; ++in)
                    acc[im][in] = __builtin_amdgcn_mfma_f32_16x16x32_f16(
                        a[im], b[in], acc[im][in], 0, 0, 0);
        }
        __syncthreads();
    }

    // epilogue: +bias, row sum-of-squares (partial over this wave's 64 cols)
    float h[2][4][4];
    float psum[2][4];
    for (int im = 0; im < 2; ++im)
        for (int reg = 0; reg < 4; ++reg) {
            float p = 0.f;
            for (int in = 0; in < 4; ++in) {
                int col = wn * 64 + in * 16 + l16;
                float v = acc[im][in][reg] + biasS[col];
                h[im][in][reg] = v;
                p += v * v;
            }
            p += __shfl_xor(p, 1);
            p += __shfl_xor(p, 2);
            p += __shfl_xor(p, 4);
            p += __shfl_xor(p, 8);
            psum[im][reg] = p;
        }
    if (l16 == 0)
        for (int im = 0; im < 2; ++im)
            for (int reg = 0; reg < 4; ++reg)
                redS[wm * 32 + im * 16 + lhi * 4 + reg][wn] = psum[im][reg];
    __syncthreads();
    if (tid < 64) invS[tid] = rsqrtf(redS[tid][0] + redS[tid][1]);
    __syncthreads();

    for (int im = 0; im < 2; ++im)
        for (int in = 0; in < 4; ++in)
            for (int reg = 0; reg < 4; ++reg) {
                int row = wm * 32 + im * 16 + lhi * 4 + reg;
                int col = wn * 64 + in * 16 + l16;
                out[(size_t)(r0 + row) * F_DIM + col] =
                    (half_t)(h[im][in][reg] * invS[row]);
            }
}

// ---------------------------------------------------------------------------
// Loss: 128x128 tile of fs·ft^T (K=128, one LDS pass), fused epilogue.
// grid = (64, 64); block = 256.  LDS = 64 KB (XOR-swizzled, no pad).
// ---------------------------------------------------------------------------
__global__ __launch_bounds__(256, 2) void loss_kernel(
    const half_t* __restrict__ FS, const half_t* __restrict__ FT,
    const int* __restrict__ y, double* __restrict__ partials)
{
    __shared__ uint4 As4[128 * 16];   // 32 KB, [row][chunk^(row&15)]
    __shared__ uint4 Bs4[128 * 16];   // 32 KB

    const int tid = threadIdx.x;
    const int i0  = blockIdx.x * 128;
    const int j0  = blockIdx.y * 128;

    for (int i = 0; i < 8; ++i) {
        int f = tid + i * 256;           // 0..2047
        int row = f >> 4, c = f & 15;    // 16 x 16B chunks per 256B row
        int sw = c ^ (row & 15);
        As4[row * 16 + sw] = *(const uint4*)(FS + (size_t)(i0 + row) * F_DIM + c * 8);
        Bs4[row * 16 + sw] = *(const uint4*)(FT + (size_t)(j0 + row) * F_DIM + c * 8);
    }
    __syncthreads();

    const int lane = tid & 63;
    const int w    = tid >> 6;
    const int wm   = w >> 1, wn = w & 1;  // wave quadrant: 64x64
    const int l16  = lane & 15, lhi = lane >> 4;

    f32x4 acc[4][4];
    for (int im = 0; im < 4; ++im)
        for (int in = 0; in < 4; ++in)
            acc[im][in] = f32x4{0.f, 0.f, 0.f, 0.f};

    for (int kk = 0; kk < 4; ++kk) {
        halfx8 a[4], b[4];
        for (int im = 0; im < 4; ++im) {
            int r = wm * 64 + im * 16 + l16;
            a[im] = *(const halfx8*)&As4[r * 16 + ((kk * 4 + lhi) ^ (r & 15))];
        }
        for (int in = 0; in < 4; ++in) {
            int r = wn * 64 + in * 16 + l16;
            b[in] = *(const halfx8*)&Bs4[r * 16 + ((kk * 4 + lhi) ^ (r & 15))];
        }
        for (int im = 0; im < 4; ++im)
            for (int in = 0; in < 4; ++in)
                acc[im][in] = __builtin_amdgcn_mfma_f32_16x16x32_f16(
                    a[im], b[in], acc[im][in], 0, 0, 0);
    }
    __syncthreads();   // done reading As4/Bs4 -> safe to reuse LDS

    int*   yrl  = (int*)As4;        // 128 ints
    int*   ycl  = yrl + 128;        // 128 ints
    float* wsum = (float*)(ycl + 128);
    if (tid < 128) yrl[tid] = y[i0 + tid];
    else           ycl[tid - 128] = y[j0 + tid - 128];
    __syncthreads();

    float local = 0.f;
    for (int im = 0; im < 4; ++im) {
        for (int reg = 0; reg < 4; ++reg) {
            int il = wm * 64 + im * 16 + lhi * 4 + reg;   // C row (fs index)
            int yi = yrl[il];
            int gi = i0 + il;
            for (int in = 0; in < 4; ++in) {
                int jl = wn * 64 + in * 16 + l16;          // C col (ft index)
                float s  = acc[im][in][reg];
                float sT = s * INV_T;
                float e  = __expf(sT);
                float l  = __logf(e + EPS_C);
                float term = (yi == ycl[jl]) ? (sT - l) : (LOG_EPS - l);
                if (gi != (j0 + jl)) local += term;
            }
        }
    }
    for (int m = 1; m < 64; m <<= 1) local += __shfl_xor(local, m);
    if (lane == 0) wsum[w] = local;
    __syncthreads();
    if (tid == 0)
        partials[blockIdx.y * gridDim.x + blockIdx.x] =
            ((double)wsum[0] + (double)wsum[1]) + ((double)wsum[2] + (double)wsum[3]);
}

// ---------------------------------------------------------------------------
__global__ __launch_bounds__(256) void finalize_kernel(
    const double* __restrict__ partials, float* __restrict__ out)
{
    __shared__ double sh[4];
    double loc = 0.0;
    for (int i = threadIdx.x; i < 4096; i += 256) loc += partials[i];
    for (int m = 1; m < 64; m <<= 1) loc += __shfl_xor(loc, m);
    int lane = threadIdx.x & 63, w = threadIdx.x >> 6;
    if (lane == 0) sh[w] = loc;
    __syncthreads();
    if (threadIdx.x == 0)
        out[0] = (float)(-(sh[0] + sh[1] + sh[2] + sh[3]) / (double)B_TOT);
}

// ---------------------------------------------------------------------------
extern "C" void kernel_launch(void* const* d_in, const int* in_sizes, int n_in,
                              void* d_out, int out_size, void* d_ws, size_t ws_size,
                              hipStream_t stream)
{
    // Workspace layout: [partials 32KB | pad to 64KB | fs 2MB | ft 2MB]
    const size_t WS_NEEDED = (64 << 10) + (4 << 20);
    if (ws_size < WS_NEEDED) {
        // Undersized scratch: do nothing -> readable absmax failure instead of
        // an OOB memory fault that kills the container.
        return;
    }

    const float* f_s = (const float*)d_in[0];
    const float* f_t = (const float*)d_in[1];
    const int*   y   = (const int*)d_in[2];
    const float* W_s = (const float*)d_in[3];
    const float* b_s = (const float*)d_in[4];
    const float* W_t = (const float*)d_in[5];
    const float* b_t = (const float*)d_in[6];
    float* out = (float*)d_out;

    char* ws = (char*)d_ws;
    double* partials = (double*)ws;                          // 32 KB
    half_t* fs = (half_t*)(ws + (64 << 10));                 // 2 MB
    half_t* ft = (half_t*)(ws + (64 << 10) + (2 << 20));     // 2 MB

    embed_kernel<<<dim3(128, 2), 256, 0, stream>>>(f_s, f_t, W_s, W_t, b_s, b_t, fs, ft);
    loss_kernel<<<dim3(64, 64), 256, 0, stream>>>(fs, ft, y, partials);
    finalize_kernel<<<1, 256, 0, stream>>>(partials, out);
    (void)in_sizes; (void)n_in; (void)out_size;
}

// Round 6
// 215.861 us; speedup vs baseline: 1.0989x; 1.0989x over previous
//
#include <hip/hip_runtime.h>
#include <math.h>

// CRDLoss on MI355X.
// Phase 1: embed (GEMM 8192x2048x128 + bias + L2 norm) -> fp16 embeddings in ws.
//          Double-buffered LDS, one barrier per K-iter (R3 was latency-bound:
//          occupancy 10%, VALUBusy 9%, 85 us vs 21 us HBM floor).
// Phase 2: 8192x8192 similarity via f16 MFMA, fused exp/log epilogue.
//          LDS 33 KB (two 64-wide K-chunks).
// Phase 3: reduce 4096 partials -> out[0] = -(sum)/B.
// R6: dropped __launch_bounds__(256,4) on loss_kernel (forced <=128 VGPR =>
//     scratch spills — the only untested novelty vs the R3 pass). Natural
//     VGPR alloc, occupancy set by LDS/VGPR without spilling.

typedef _Float16 half_t;
typedef half_t halfx4 __attribute__((ext_vector_type(4)));
typedef half_t halfx8 __attribute__((ext_vector_type(8)));
typedef float f32x4 __attribute__((ext_vector_type(4)));

#define B_TOT   8192
#define K_EMB   2048
#define F_DIM   128
#define INV_T   14.285714285714286f   // 1/0.07
#define EPS_C   0.97f
#define LOG_EPS (-0.030459207485f)    // ln(0.97)

// ---------------------------------------------------------------------------
// Embed: 64-row tile x all 128 cols, BK=64, double-buffered.
// grid = (128, 2); block = 256 (4 waves: 2x2 quadrants of 32x64).
// ---------------------------------------------------------------------------
__global__ __launch_bounds__(256) void embed_kernel(
    const float* __restrict__ Xs, const float* __restrict__ Xt,
    const float* __restrict__ Ws, const float* __restrict__ Wt,
    const float* __restrict__ bs, const float* __restrict__ bt,
    half_t* __restrict__ outs, half_t* __restrict__ outt)
{
    const float* X; const float* W; const float* bias; half_t* out;
    if (blockIdx.y == 0) { X = Xs; W = Ws; bias = bs; out = outs; }
    else                 { X = Xt; W = Wt; bias = bt; out = outt; }

    // +8 pad: row stride 72 halves = 144 B
    __shared__ half_t As[2][64][72];     // 18 KB
    __shared__ half_t Bs[2][128][72];    // 36 KB
    __shared__ float  biasS[128];
    __shared__ float  redS[64][2];
    __shared__ float  invS[64];

    const int tid = threadIdx.x;
    const int r0  = blockIdx.x * 64;
    if (tid < 128) biasS[tid] = bias[tid];

    const int lane = tid & 63;
    const int w    = tid >> 6;
    const int wm   = w >> 1, wn = w & 1;
    const int l16  = lane & 15, lhi = lane >> 4;

    f32x4 acc[2][4];
    for (int im = 0; im < 2; ++im)
        for (int in = 0; in < 4; ++in)
            acc[im][in] = f32x4{0.f, 0.f, 0.f, 0.f};

    // per-thread staging coordinates (row, k-quad) for A (4x) and B (8x)
    const int ar[4] = { (tid) >> 4, (tid + 256) >> 4, (tid + 512) >> 4, (tid + 768) >> 4 };
    const int ak = (tid & 15) * 4;

    float4 na[4], nb[8];

    // prologue: load + convert tile 0 into buffer 0
#pragma unroll
    for (int i = 0; i < 4; ++i)
        na[i] = *(const float4*)(X + (size_t)(r0 + ar[i]) * K_EMB + ak);
#pragma unroll
    for (int i = 0; i < 8; ++i)
        nb[i] = *(const float4*)(W + (size_t)((tid + i * 256) >> 4) * K_EMB + ak);
#pragma unroll
    for (int i = 0; i < 4; ++i) {
        halfx4 h4 = {(half_t)na[i].x, (half_t)na[i].y, (half_t)na[i].z, (half_t)na[i].w};
        *(halfx4*)&As[0][ar[i]][ak] = h4;
    }
#pragma unroll
    for (int i = 0; i < 8; ++i) {
        halfx4 h4 = {(half_t)nb[i].x, (half_t)nb[i].y, (half_t)nb[i].z, (half_t)nb[i].w};
        *(halfx4*)&Bs[0][(tid + i * 256) >> 4][ak] = h4;
    }
    __syncthreads();

    for (int it = 0; it < 32; ++it) {
        const int cur = it & 1;
        if (it < 31) {
            const int kb = (it + 1) * 64;
#pragma unroll
            for (int i = 0; i < 4; ++i)
                na[i] = *(const float4*)(X + (size_t)(r0 + ar[i]) * K_EMB + kb + ak);
#pragma unroll
            for (int i = 0; i < 8; ++i)
                nb[i] = *(const float4*)(W + (size_t)((tid + i * 256) >> 4) * K_EMB + kb + ak);
        }
#pragma unroll
        for (int kk = 0; kk < 2; ++kk) {          // MFMA on current buffer
            halfx8 a[2], b[4];
#pragma unroll
            for (int im = 0; im < 2; ++im)
                a[im] = *(const halfx8*)&As[cur][wm * 32 + im * 16 + l16][kk * 32 + lhi * 8];
#pragma unroll
            for (int in = 0; in < 4; ++in)
                b[in] = *(const halfx8*)&Bs[cur][wn * 64 + in * 16 + l16][kk * 32 + lhi * 8];
#pragma unroll
            for (int im = 0; im < 2; ++im)
#pragma unroll
                for (int in = 0; in < 4; ++in)
                    acc[im][in] = __builtin_amdgcn_mfma_f32_16x16x32_f16(
                        a[im], b[in], acc[im][in], 0, 0, 0);
        }
        if (it < 31) {                            // convert + fill other buffer
            const int nxt = cur ^ 1;
#pragma unroll
            for (int i = 0; i < 4; ++i) {
                halfx4 h4 = {(half_t)na[i].x, (half_t)na[i].y, (half_t)na[i].z, (half_t)na[i].w};
                *(halfx4*)&As[nxt][ar[i]][ak] = h4;
            }
#pragma unroll
            for (int i = 0; i < 8; ++i) {
                halfx4 h4 = {(half_t)nb[i].x, (half_t)nb[i].y, (half_t)nb[i].z, (half_t)nb[i].w};
                *(halfx4*)&Bs[nxt][(tid + i * 256) >> 4][ak] = h4;
            }
        }
        __syncthreads();
    }

    // epilogue: +bias, row sum-of-squares, normalize, fp16 store
    float h[2][4][4];
    float psum[2][4];
    for (int im = 0; im < 2; ++im)
        for (int reg = 0; reg < 4; ++reg) {
            float p = 0.f;
            for (int in = 0; in < 4; ++in) {
                int col = wn * 64 + in * 16 + l16;
                float v = acc[im][in][reg] + biasS[col];
                h[im][in][reg] = v;
                p += v * v;
            }
            p += __shfl_xor(p, 1);
            p += __shfl_xor(p, 2);
            p += __shfl_xor(p, 4);
            p += __shfl_xor(p, 8);
            psum[im][reg] = p;
        }
    if (l16 == 0)
        for (int im = 0; im < 2; ++im)
            for (int reg = 0; reg < 4; ++reg)
                redS[wm * 32 + im * 16 + lhi * 4 + reg][wn] = psum[im][reg];
    __syncthreads();
    if (tid < 64) invS[tid] = rsqrtf(redS[tid][0] + redS[tid][1]);
    __syncthreads();

    for (int im = 0; im < 2; ++im)
        for (int in = 0; in < 4; ++in)
            for (int reg = 0; reg < 4; ++reg) {
                int row = wm * 32 + im * 16 + lhi * 4 + reg;
                int col = wn * 64 + in * 16 + l16;
                out[(size_t)(r0 + row) * F_DIM + col] =
                    (half_t)(h[im][in][reg] * invS[row]);
            }
}

// ---------------------------------------------------------------------------
// Loss: 128x128 tile of fs·ft^T, K=128 in two 64-wide LDS chunks (33 KB LDS).
// grid = (64, 64); block = 256.  No forced occupancy (avoid VGPR spills).
// ---------------------------------------------------------------------------
__global__ __launch_bounds__(256) void loss_kernel(
    const half_t* __restrict__ FS, const half_t* __restrict__ FT,
    const int* __restrict__ y, double* __restrict__ partials)
{
    __shared__ uint4 As4[128 * 8];   // 16 KB: 128 rows x 8 chunks (64 halves)
    __shared__ uint4 Bs4[128 * 8];   // 16 KB
    __shared__ int   yrl[128], ycl[128];
    __shared__ float wsum[4];

    const int tid = threadIdx.x;
    const int i0  = blockIdx.x * 128;
    const int j0  = blockIdx.y * 128;

    if (tid < 128) yrl[tid] = y[i0 + tid];
    else           ycl[tid - 128] = y[j0 + tid - 128];

    const int lane = tid & 63;
    const int w    = tid >> 6;
    const int wm   = w >> 1, wn = w & 1;
    const int l16  = lane & 15, lhi = lane >> 4;

    // stage K-chunk 0 (halves 0..63 of each row), XOR-swizzled
#pragma unroll
    for (int i = 0; i < 4; ++i) {
        int f = tid + i * 256;          // 0..1023
        int row = f >> 3, c = f & 7;
        As4[row * 8 + (c ^ (row & 7))] = *(const uint4*)(FS + (size_t)(i0 + row) * F_DIM + c * 8);
    }
#pragma unroll
    for (int i = 0; i < 4; ++i) {
        int f = tid + i * 256;
        int row = f >> 3, c = f & 7;
        Bs4[row * 8 + (c ^ (row & 7))] = *(const uint4*)(FT + (size_t)(j0 + row) * F_DIM + c * 8);
    }
    __syncthreads();

    f32x4 acc[4][4];
    for (int im = 0; im < 4; ++im)
        for (int in = 0; in < 4; ++in)
            acc[im][in] = f32x4{0.f, 0.f, 0.f, 0.f};

    for (int kc = 0; kc < 2; ++kc) {
#pragma unroll
        for (int kk = 0; kk < 2; ++kk) {
            halfx8 a[4], b[4];
#pragma unroll
            for (int im = 0; im < 4; ++im) {
                int r = wm * 64 + im * 16 + l16;
                a[im] = *(const halfx8*)&As4[r * 8 + ((kk * 4 + lhi) ^ (r & 7))];
            }
#pragma unroll
            for (int in = 0; in < 4; ++in) {
                int r = wn * 64 + in * 16 + l16;
                b[in] = *(const halfx8*)&Bs4[r * 8 + ((kk * 4 + lhi) ^ (r & 7))];
            }
#pragma unroll
            for (int im = 0; im < 4; ++im)
#pragma unroll
                for (int in = 0; in < 4; ++in)
                    acc[im][in] = __builtin_amdgcn_mfma_f32_16x16x32_f16(
                        a[im], b[in], acc[im][in], 0, 0, 0);
        }
        if (kc == 0) {
            __syncthreads();   // all reads of chunk 0 done
#pragma unroll
            for (int i = 0; i < 4; ++i) {
                int f = tid + i * 256;
                int row = f >> 3, c = f & 7;
                As4[row * 8 + (c ^ (row & 7))] =
                    *(const uint4*)(FS + (size_t)(i0 + row) * F_DIM + 64 + c * 8);
            }
#pragma unroll
            for (int i = 0; i < 4; ++i) {
                int f = tid + i * 256;
                int row = f >> 3, c = f & 7;
                Bs4[row * 8 + (c ^ (row & 7))] =
                    *(const uint4*)(FT + (size_t)(j0 + row) * F_DIM + 64 + c * 8);
            }
            __syncthreads();
        }
    }

    float local = 0.f;
    for (int im = 0; im < 4; ++im) {
        for (int reg = 0; reg < 4; ++reg) {
            int il = wm * 64 + im * 16 + lhi * 4 + reg;   // C row (fs index)
            int yi = yrl[il];
            int gi = i0 + il;
            for (int in = 0; in < 4; ++in) {
                int jl = wn * 64 + in * 16 + l16;          // C col (ft index)
                float s  = acc[im][in][reg];
                float sT = s * INV_T;
                float e  = __expf(sT);
                float l  = __logf(e + EPS_C);
                float term = (yi == ycl[jl]) ? (sT - l) : (LOG_EPS - l);
                if (gi != (j0 + jl)) local += term;
            }
        }
    }
    for (int m = 1; m < 64; m <<= 1) local += __shfl_xor(local, m);
    if (lane == 0) wsum[w] = local;
    __syncthreads();
    if (tid == 0)
        partials[blockIdx.y * gridDim.x + blockIdx.x] =
            ((double)wsum[0] + (double)wsum[1]) + ((double)wsum[2] + (double)wsum[3]);
}

// ---------------------------------------------------------------------------
__global__ __launch_bounds__(256) void finalize_kernel(
    const double* __restrict__ partials, float* __restrict__ out)
{
    __shared__ double sh[4];
    double loc = 0.0;
    for (int i = threadIdx.x; i < 4096; i += 256) loc += partials[i];
    for (int m = 1; m < 64; m <<= 1) loc += __shfl_xor(loc, m);
    int lane = threadIdx.x & 63, w = threadIdx.x >> 6;
    if (lane == 0) sh[w] = loc;
    __syncthreads();
    if (threadIdx.x == 0)
        out[0] = (float)(-(sh[0] + sh[1] + sh[2] + sh[3]) / (double)B_TOT);
}

// ---------------------------------------------------------------------------
extern "C" void kernel_launch(void* const* d_in, const int* in_sizes, int n_in,
                              void* d_out, int out_size, void* d_ws, size_t ws_size,
                              hipStream_t stream)
{
    // Workspace layout: [partials 32KB | pad to 64KB | fs 2MB | ft 2MB]
    const size_t WS_NEEDED = (64 << 10) + (4 << 20);
    if (ws_size < WS_NEEDED) return;   // readable failure instead of OOB fault

    const float* f_s = (const float*)d_in[0];
    const float* f_t = (const float*)d_in[1];
    const int*   y   = (const int*)d_in[2];
    const float* W_s = (const float*)d_in[3];
    const float* b_s = (const float*)d_in[4];
    const float* W_t = (const float*)d_in[5];
    const float* b_t = (const float*)d_in[6];
    float* out = (float*)d_out;

    char* ws = (char*)d_ws;
    double* partials = (double*)ws;                          // 32 KB
    half_t* fs = (half_t*)(ws + (64 << 10));                 // 2 MB
    half_t* ft = (half_t*)(ws + (64 << 10) + (2 << 20));     // 2 MB

    embed_kernel<<<dim3(128, 2), 256, 0, stream>>>(f_s, f_t, W_s, W_t, b_s, b_t, fs, ft);
    loss_kernel<<<dim3(64, 64), 256, 0, stream>>>(fs, ft, y, partials);
    finalize_kernel<<<1, 256, 0, stream>>>(partials, out);
    (void)in_sizes; (void)n_in; (void)out_size;
}

// Round 7
// 215.168 us; speedup vs baseline: 1.1025x; 1.0032x over previous
//
#include <hip/hip_runtime.h>
#include <math.h>

// CRDLoss on MI355X.
// Phase 0: convert W_s/W_t -> fp16 in ws (1 MB, L2-resident thereafter).
// Phase 1: embed (GEMM 8192x2048x128 + bias + L2 norm) -> fp16 embeddings.
//          R7: 32-row tiles, grid (256,2) => 2 blocks/CU (R6 was 1 block/CU,
//          occupancy 10%, 63 us vs 21 us HBM floor). B staged from fp16 W.
// Phase 2: 8192x8192 similarity via f16 MFMA, fused exp/log epilogue (R6-proven).
// Phase 3: reduce 4096 partials -> out[0] = -(sum)/B.

typedef _Float16 half_t;
typedef half_t halfx4 __attribute__((ext_vector_type(4)));
typedef half_t halfx8 __attribute__((ext_vector_type(8)));
typedef float f32x4 __attribute__((ext_vector_type(4)));

#define B_TOT   8192
#define K_EMB   2048
#define F_DIM   128
#define INV_T   14.285714285714286f   // 1/0.07
#define EPS_C   0.97f
#define LOG_EPS (-0.030459207485f)    // ln(0.97)

// ---------------------------------------------------------------------------
// W fp32 -> fp16.  grid = (256, 2); block = 256; one float4 per thread.
// ---------------------------------------------------------------------------
__global__ __launch_bounds__(256) void cvt_w_kernel(
    const float* __restrict__ Ws, const float* __restrict__ Wt,
    half_t* __restrict__ Ws16, half_t* __restrict__ Wt16)
{
    const float* src = blockIdx.y ? Wt : Ws;
    half_t* dst = blockIdx.y ? Wt16 : Ws16;
    int pos4 = blockIdx.x * 256 + threadIdx.x;      // 0..65535
    float4 v = *(const float4*)(src + (size_t)pos4 * 4);
    halfx4 h4 = {(half_t)v.x, (half_t)v.y, (half_t)v.z, (half_t)v.w};
    *(halfx4*)(dst + (size_t)pos4 * 4) = h4;
}

// ---------------------------------------------------------------------------
// Embed: 32-row tile x all 128 cols, BK=64, double-buffered LDS.
// grid = (256, 2); block = 256 (4 waves: wm=w&1 row-halves, wn=w>>1 col-halves).
// ---------------------------------------------------------------------------
__global__ __launch_bounds__(256) void embed_kernel(
    const float* __restrict__ Xs, const float* __restrict__ Xt,
    const half_t* __restrict__ Ws16, const half_t* __restrict__ Wt16,
    const float* __restrict__ bs, const float* __restrict__ bt,
    half_t* __restrict__ outs, half_t* __restrict__ outt)
{
    const float* X; const half_t* W16; const float* bias; half_t* out;
    if (blockIdx.y == 0) { X = Xs; W16 = Ws16; bias = bs; out = outs; }
    else                 { X = Xt; W16 = Wt16; bias = bt; out = outt; }

    // +8 pad: row stride 72 halves = 144 B
    __shared__ half_t As[2][32][72];     //  9.2 KB
    __shared__ half_t Bs[2][128][72];    // 36.9 KB
    __shared__ float  biasS[128];
    __shared__ float  redS[32][2];
    __shared__ float  invS[32];

    const int tid = threadIdx.x;
    const int r0  = blockIdx.x * 32;
    if (tid < 128) biasS[tid] = bias[tid];

    const int lane = tid & 63;
    const int w    = tid >> 6;
    const int wm   = w & 1, wn = w >> 1;     // rows 16*wm, cols 64*wn
    const int l16  = lane & 15, lhi = lane >> 4;

    f32x4 acc[4];
    for (int in = 0; in < 4; ++in) acc[in] = f32x4{0.f, 0.f, 0.f, 0.f};

    // A staging coords: 512 float4 -> 2/thread; f = tid + i*256
    const int ar0 = tid >> 4, ar1 = (tid + 256) >> 4;   // rows 0..31
    const int akq = (tid & 15) * 4;                      // k-quad offset (floats)
    // B staging coords: 1024 uint4 -> 4/thread; f = tid + i*256
    const int bc  = (tid & 7) * 8;                       // 8 halves per chunk

    float4 na[2]; uint4 nb[4];

    // prologue: tile 0 into buffer 0
    na[0] = *(const float4*)(X + (size_t)(r0 + ar0) * K_EMB + akq);
    na[1] = *(const float4*)(X + (size_t)(r0 + ar1) * K_EMB + akq);
#pragma unroll
    for (int i = 0; i < 4; ++i)
        nb[i] = *(const uint4*)(W16 + (size_t)((tid + i * 256) >> 3) * K_EMB + bc);
    {
        halfx4 h0 = {(half_t)na[0].x, (half_t)na[0].y, (half_t)na[0].z, (half_t)na[0].w};
        halfx4 h1 = {(half_t)na[1].x, (half_t)na[1].y, (half_t)na[1].z, (half_t)na[1].w};
        *(halfx4*)&As[0][ar0][akq] = h0;
        *(halfx4*)&As[0][ar1][akq] = h1;
#pragma unroll
        for (int i = 0; i < 4; ++i)
            *(uint4*)&Bs[0][(tid + i * 256) >> 3][bc] = nb[i];
    }
    __syncthreads();

    for (int it = 0; it < 32; ++it) {
        const int cur = it & 1;
        if (it < 31) {
            const int kb = (it + 1) * 64;
            na[0] = *(const float4*)(X + (size_t)(r0 + ar0) * K_EMB + kb + akq);
            na[1] = *(const float4*)(X + (size_t)(r0 + ar1) * K_EMB + kb + akq);
#pragma unroll
            for (int i = 0; i < 4; ++i)
                nb[i] = *(const uint4*)(W16 + (size_t)((tid + i * 256) >> 3) * K_EMB + kb + bc);
        }
#pragma unroll
        for (int kk = 0; kk < 2; ++kk) {
            halfx8 a, b[4];
            a = *(const halfx8*)&As[cur][wm * 16 + l16][kk * 32 + lhi * 8];
#pragma unroll
            for (int in = 0; in < 4; ++in)
                b[in] = *(const halfx8*)&Bs[cur][wn * 64 + in * 16 + l16][kk * 32 + lhi * 8];
#pragma unroll
            for (int in = 0; in < 4; ++in)
                acc[in] = __builtin_amdgcn_mfma_f32_16x16x32_f16(a, b[in], acc[in], 0, 0, 0);
        }
        if (it < 31) {
            const int nxt = cur ^ 1;
            halfx4 h0 = {(half_t)na[0].x, (half_t)na[0].y, (half_t)na[0].z, (half_t)na[0].w};
            halfx4 h1 = {(half_t)na[1].x, (half_t)na[1].y, (half_t)na[1].z, (half_t)na[1].w};
            *(halfx4*)&As[nxt][ar0][akq] = h0;
            *(halfx4*)&As[nxt][ar1][akq] = h1;
#pragma unroll
            for (int i = 0; i < 4; ++i)
                *(uint4*)&Bs[nxt][(tid + i * 256) >> 3][bc] = nb[i];
        }
        __syncthreads();
    }

    // epilogue: +bias, row sum-of-squares, normalize, fp16 store
    float h[4][4];
    float psum[4];
#pragma unroll
    for (int reg = 0; reg < 4; ++reg) {
        float p = 0.f;
#pragma unroll
        for (int in = 0; in < 4; ++in) {
            int col = wn * 64 + in * 16 + l16;
            float v = acc[in][reg] + biasS[col];
            h[in][reg] = v;
            p += v * v;
        }
        p += __shfl_xor(p, 1);
        p += __shfl_xor(p, 2);
        p += __shfl_xor(p, 4);
        p += __shfl_xor(p, 8);
        psum[reg] = p;
    }
    if (l16 == 0)
#pragma unroll
        for (int reg = 0; reg < 4; ++reg)
            redS[wm * 16 + lhi * 4 + reg][wn] = psum[reg];
    __syncthreads();
    if (tid < 32) invS[tid] = rsqrtf(redS[tid][0] + redS[tid][1]);
    __syncthreads();

#pragma unroll
    for (int in = 0; in < 4; ++in)
#pragma unroll
        for (int reg = 0; reg < 4; ++reg) {
            int row = wm * 16 + lhi * 4 + reg;
            int col = wn * 64 + in * 16 + l16;
            out[(size_t)(r0 + row) * F_DIM + col] = (half_t)(h[in][reg] * invS[row]);
        }
}

// ---------------------------------------------------------------------------
// Loss: 128x128 tile of fs·ft^T, K=128 in two 64-wide LDS chunks (33 KB LDS).
// grid = (64, 64); block = 256.  (unchanged from R6 pass)
// ---------------------------------------------------------------------------
__global__ __launch_bounds__(256) void loss_kernel(
    const half_t* __restrict__ FS, const half_t* __restrict__ FT,
    const int* __restrict__ y, double* __restrict__ partials)
{
    __shared__ uint4 As4[128 * 8];   // 16 KB
    __shared__ uint4 Bs4[128 * 8];   // 16 KB
    __shared__ int   yrl[128], ycl[128];
    __shared__ float wsum[4];

    const int tid = threadIdx.x;
    const int i0  = blockIdx.x * 128;
    const int j0  = blockIdx.y * 128;

    if (tid < 128) yrl[tid] = y[i0 + tid];
    else           ycl[tid - 128] = y[j0 + tid - 128];

    const int lane = tid & 63;
    const int w    = tid >> 6;
    const int wm   = w >> 1, wn = w & 1;
    const int l16  = lane & 15, lhi = lane >> 4;

#pragma unroll
    for (int i = 0; i < 4; ++i) {
        int f = tid + i * 256;
        int row = f >> 3, c = f & 7;
        As4[row * 8 + (c ^ (row & 7))] = *(const uint4*)(FS + (size_t)(i0 + row) * F_DIM + c * 8);
    }
#pragma unroll
    for (int i = 0; i < 4; ++i) {
        int f = tid + i * 256;
        int row = f >> 3, c = f & 7;
        Bs4[row * 8 + (c ^ (row & 7))] = *(const uint4*)(FT + (size_t)(j0 + row) * F_DIM + c * 8);
    }
    __syncthreads();

    f32x4 acc[4][4];
    for (int im = 0; im < 4; ++im)
        for (int in = 0; in < 4; ++in)
            acc[im][in] = f32x4{0.f, 0.f, 0.f, 0.f};

    for (int kc = 0; kc < 2; ++kc) {
#pragma unroll
        for (int kk = 0; kk < 2; ++kk) {
            halfx8 a[4], b[4];
#pragma unroll
            for (int im = 0; im < 4; ++im) {
                int r = wm * 64 + im * 16 + l16;
                a[im] = *(const halfx8*)&As4[r * 8 + ((kk * 4 + lhi) ^ (r & 7))];
            }
#pragma unroll
            for (int in = 0; in < 4; ++in) {
                int r = wn * 64 + in * 16 + l16;
                b[in] = *(const halfx8*)&Bs4[r * 8 + ((kk * 4 + lhi) ^ (r & 7))];
            }
#pragma unroll
            for (int im = 0; im < 4; ++im)
#pragma unroll
                for (int in = 0; in < 4; ++in)
                    acc[im][in] = __builtin_amdgcn_mfma_f32_16x16x32_f16(
                        a[im], b[in], acc[im][in], 0, 0, 0);
        }
        if (kc == 0) {
            __syncthreads();
#pragma unroll
            for (int i = 0; i < 4; ++i) {
                int f = tid + i * 256;
                int row = f >> 3, c = f & 7;
                As4[row * 8 + (c ^ (row & 7))] =
                    *(const uint4*)(FS + (size_t)(i0 + row) * F_DIM + 64 + c * 8);
            }
#pragma unroll
            for (int i = 0; i < 4; ++i) {
                int f = tid + i * 256;
                int row = f >> 3, c = f & 7;
                Bs4[row * 8 + (c ^ (row & 7))] =
                    *(const uint4*)(FT + (size_t)(j0 + row) * F_DIM + 64 + c * 8);
            }
            __syncthreads();
        }
    }

    float local = 0.f;
    for (int im = 0; im < 4; ++im) {
        for (int reg = 0; reg < 4; ++reg) {
            int il = wm * 64 + im * 16 + lhi * 4 + reg;
            int yi = yrl[il];
            int gi = i0 + il;
            for (int in = 0; in < 4; ++in) {
                int jl = wn * 64 + in * 16 + l16;
                float s  = acc[im][in][reg];
                float sT = s * INV_T;
                float e  = __expf(sT);
                float l  = __logf(e + EPS_C);
                float term = (yi == ycl[jl]) ? (sT - l) : (LOG_EPS - l);
                if (gi != (j0 + jl)) local += term;
            }
        }
    }
    for (int m = 1; m < 64; m <<= 1) local += __shfl_xor(local, m);
    if (lane == 0) wsum[w] = local;
    __syncthreads();
    if (tid == 0)
        partials[blockIdx.y * gridDim.x + blockIdx.x] =
            ((double)wsum[0] + (double)wsum[1]) + ((double)wsum[2] + (double)wsum[3]);
}

// ---------------------------------------------------------------------------
__global__ __launch_bounds__(256) void finalize_kernel(
    const double* __restrict__ partials, float* __restrict__ out)
{
    __shared__ double sh[4];
    double loc = 0.0;
    for (int i = threadIdx.x; i < 4096; i += 256) loc += partials[i];
    for (int m = 1; m < 64; m <<= 1) loc += __shfl_xor(loc, m);
    int lane = threadIdx.x & 63, w = threadIdx.x >> 6;
    if (lane == 0) sh[w] = loc;
    __syncthreads();
    if (threadIdx.x == 0)
        out[0] = (float)(-(sh[0] + sh[1] + sh[2] + sh[3]) / (double)B_TOT);
}

// ---------------------------------------------------------------------------
extern "C" void kernel_launch(void* const* d_in, const int* in_sizes, int n_in,
                              void* d_out, int out_size, void* d_ws, size_t ws_size,
                              hipStream_t stream)
{
    // ws layout: [partials 32KB | pad->64KB | fs 2MB | ft 2MB | Ws16 512KB | Wt16 512KB]
    const size_t WS_NEEDED = (64 << 10) + (4 << 20) + (1 << 20);
    if (ws_size < WS_NEEDED) return;   // readable failure instead of OOB fault

    const float* f_s = (const float*)d_in[0];
    const float* f_t = (const float*)d_in[1];
    const int*   y   = (const int*)d_in[2];
    const float* W_s = (const float*)d_in[3];
    const float* b_s = (const float*)d_in[4];
    const float* W_t = (const float*)d_in[5];
    const float* b_t = (const float*)d_in[6];
    float* out = (float*)d_out;

    char* ws = (char*)d_ws;
    double* partials = (double*)ws;                               // 32 KB
    half_t* fs   = (half_t*)(ws + (64 << 10));                    // 2 MB
    half_t* ft   = (half_t*)(ws + (64 << 10) + (2 << 20));        // 2 MB
    half_t* Ws16 = (half_t*)(ws + (64 << 10) + (4 << 20));        // 512 KB
    half_t* Wt16 = (half_t*)(ws + (64 << 10) + (4 << 20) + (512 << 10));

    cvt_w_kernel<<<dim3(256, 2), 256, 0, stream>>>(W_s, W_t, Ws16, Wt16);
    embed_kernel<<<dim3(256, 2), 256, 0, stream>>>(f_s, f_t, Ws16, Wt16, b_s, b_t, fs, ft);
    loss_kernel<<<dim3(64, 64), 256, 0, stream>>>(fs, ft, y, partials);
    finalize_kernel<<<1, 256, 0, stream>>>(partials, out);
    (void)in_sizes; (void)n_in; (void)out_size;
}